// Round 4
// baseline (59.745 us; speedup 1.0000x reference)
//
#include <hip/hip_runtime.h>

#define NIMG 16
#define NRBF 128
#define ROWS 256
#define COLS 256
#define PIX  (ROWS * COLS)
#define TPB  1024                  // 16 waves/block -> 4 waves/SIMD (was 1)
#define TILE 64                    // 64x64 px per block
#define TPI  16                    // tiles per image (4x4)
#define KSTR 136                   // padded k-stride in halfs (272 B, 16B-aligned)

typedef _Float16 f16x8 __attribute__((ext_vector_type(8)));
typedef float    f32x4 __attribute__((ext_vector_type(4)));

// Separable RBF as a rank-128 GEMM on matrix cores, 64x64-px square tiles:
//   C[y][x] = sum_k (a_k * gy[k][y]) * gx[k][x]
// v2: TPB 256 -> 1024. The v1 grid (256 blk x 4 waves) left exactly 1
// wave/SIMD -- every LDS-load->fmaf->exp2->cvt chain and every ds_read->
// MFMA chain was latency-exposed. Same total work, 4x TLP:
//   phase 1: each thread does ONE 8-k chunk (16 exps, was 64)
//   phase 2: each wave owns ONE 16x16 ctile (4 mfma chain, was 4x4)
// v2.1: float2 center load (cold-phase micro-polish). Structure unchanged.
// Bank audit: KSTR=136 (68 dw/row) -> all b128 LDS ops hit the uniform
// 8-dword/bank wave64 floor, zero excess conflicts.
// Frag layouts verified (m89/m91): A/B lane l -> [free=l&15][k=(l>>4)*8+j];
// C/D col=l&15, row=(l>>4)*4+reg.
// NOTE: rounds 0-3 all failed on GPUAcquisitionTimeout -- this candidate
// is unmeasured; do not stack further structural changes until it benches.
__global__ __launch_bounds__(TPB) void rbf_mfma_kernel(
    const float* __restrict__ centers,      // (NIMG, NRBF, 2)
    const float* __restrict__ covariances,  // (NIMG, NRBF, 3)
    const float* __restrict__ amplitudes,   // (NIMG, NRBF, 1)
    float* __restrict__ out)                // (NIMG, ROWS, COLS)
{
    __shared__ _Float16 gxT[TILE][KSTR];   // B tile: [col][k]   17,408 B
    __shared__ _Float16 gaT[TILE][KSTR];   // A tile: [row][k]   17,408 B
    __shared__ float2   pxs[NRBF];         // (nscx, s)           1,024 B
    __shared__ float4   pya[NRBF];         // (nscy, s, a, 0)     2,048 B

    const int tid  = threadIdx.x;
    const int lane = tid & 63;
    const int wave = tid >> 6;             // 0..15
    const int img  = blockIdx.x >> 4;      // / TPI
    const int tile = blockIdx.x & 15;      // % TPI
    const int rb   = (tile >> 2) * TILE;   // tile row base
    const int cb   = (tile & 3) * TILE;    // tile col base

    const float LOG2E = 1.4426950408889634f;

    if (tid < NRBF) {
        const int k = tid;
        const float2 cxy = *(const float2*)&centers[(img * NRBF + k) * 2];
        const float c0 = covariances[(img * NRBF + k) * 3 + 0];
        const float a  = amplitudes[img * NRBF + k];
        // s = sqrt(0.5*log2e)*exp(-c0): folds 0.5/sigma^2 and log2e into coords
        const float s = 0.8493218002880190f * __builtin_amdgcn_exp2f(-c0 * LOG2E);
        pxs[k] = make_float2(-s * cxy.x, s);
        pya[k] = make_float4(-s * cxy.y, s, a, 0.0f);
    }
    __syncthreads();

    // phase 1: thread t -> col/row (t&63), ONE k-chunk [(t>>6)*8, +8)
    const int   cc  = tid & 63;
    const int   kb0 = (tid >> 6) * 8;
    const float xf  = (float)(cb + cc);
    const float yf  = (float)(rb + cc);

    {
        f16x8 hx, ha;
#pragma unroll
        for (int j = 0; j < 8; ++j) {
            const float2 px = pxs[kb0 + j];            // LDS broadcast
            const float dx = fmaf(xf, px.y, px.x);
            hx[j] = (_Float16)__builtin_amdgcn_exp2f(-dx * dx);
            const float4 py = pya[kb0 + j];
            const float dy = fmaf(yf, py.y, py.x);
            ha[j] = (_Float16)(py.z * __builtin_amdgcn_exp2f(-dy * dy));
        }
        *(f16x8*)&gxT[cc][kb0] = hx;
        *(f16x8*)&gaT[cc][kb0] = ha;
    }
    __syncthreads();

    // phase 2: wave w -> row band (w>>2)*16, col tile (w&3)*16; 4 mfma
    const int n   = lane & 15;
    const int q   = lane >> 4;
    const int rb2 = (wave >> 2) * 16;
    const int cb2 = (wave &  3) * 16;

    f32x4 acc = {0, 0, 0, 0};
#pragma unroll
    for (int kc = 0; kc < 4; ++kc) {
        const int kb = kc * 32 + q * 8;
        const f16x8 afr = *(const f16x8*)&gaT[rb2 + n][kb];
        const f16x8 bfr = *(const f16x8*)&gxT[cb2 + n][kb];
        acc = __builtin_amdgcn_mfma_f32_16x16x32_f16(afr, bfr, acc, 0, 0, 0);
    }

    // epilogue: sigmoid + store. C/D: col = n (within ctile), row = q*4 + r.
#define SIG(v) __builtin_amdgcn_rcpf(1.0f + __builtin_amdgcn_exp2f(-(v) * LOG2E))
    float* base = out + img * PIX + (rb + rb2) * COLS + cb + cb2 + n;
#pragma unroll
    for (int r = 0; r < 4; ++r) {
        base[(q * 4 + r) * COLS] = SIG(acc[r]);
    }
#undef SIG
}

extern "C" void kernel_launch(void* const* d_in, const int* in_sizes, int n_in,
                              void* d_out, int out_size, void* d_ws, size_t ws_size,
                              hipStream_t stream) {
    const float* centers     = (const float*)d_in[0];
    const float* covariances = (const float*)d_in[1];
    const float* amplitudes  = (const float*)d_in[2];
    float* out = (float*)d_out;

    dim3 grid(NIMG * TPI);   // 256 blocks -> 1 block/CU, 16 waves each
    dim3 block(TPB);
    rbf_mfma_kernel<<<grid, block, 0, stream>>>(centers, covariances, amplitudes, out);
}